// Round 1
// baseline (2533.277 us; speedup 1.0000x reference)
//
#include <hip/hip_runtime.h>

#define SEQ 2048
#define D 128

typedef float v2f __attribute__((ext_vector_type(2)));
typedef float v4f __attribute__((ext_vector_type(4)));
#define LO2(v) __builtin_shufflevector(v, v, 0, 1)
#define HI2(v) __builtin_shufflevector(v, v, 2, 3)

// ---------------------------------------------------------------------------
// Kernel 1: per-step J-independent quantities (fully parallel), UNNORMALIZED.
// (unchanged from R15)
// ---------------------------------------------------------------------------
__global__ __launch_bounds__(256) void precompute_kernel(
    const float* __restrict__ q, const float* __restrict__ k, const float* __restrict__ v,
    float* __restrict__ U, float* __restrict__ sl, float* __restrict__ kqq,
    float* __restrict__ vv, float* __restrict__ kq_adj, float* __restrict__ vv_adj,
    float* __restrict__ kU_adj, double* __restrict__ invl)
{
    const int s = blockIdx.x;
    const int tid = threadIdx.x;

    __shared__ float ks[D];
    __shared__ float vs[D];
    __shared__ float alpha[SEQ];
    __shared__ float red[8];
    __shared__ float upart[256];

    if (tid < D) ks[tid] = k[s * D + tid];
    else if (tid < 2 * D) vs[tid - D] = v[s * D + (tid - D)];
    __syncthreads();

    float p_a2 = 0.f, p_ab = 0.f;
    for (int i = tid; i <= s; i += 256) {
        const float4* qr = (const float4*)(q + (size_t)i * D);
        const float4* vr = (const float4*)(v + (size_t)i * D);
        float a = 0.f, b = 0.f;
#pragma unroll
        for (int j = 0; j < D / 4; ++j) {
            float4 q4 = qr[j];
            float4 v4 = vr[j];
            a += q4.x * ks[4 * j + 0] + q4.y * ks[4 * j + 1] + q4.z * ks[4 * j + 2] + q4.w * ks[4 * j + 3];
            b += v4.x * vs[4 * j + 0] + v4.y * vs[4 * j + 1] + v4.z * vs[4 * j + 2] + v4.w * vs[4 * j + 3];
        }
        alpha[i] = a;
        p_a2 += a * a;
        p_ab += a * b;
        if (i == s) vv[s] = b;  // v_s . v_s
    }
#pragma unroll
    for (int off = 1; off < 64; off <<= 1) {
        p_a2 += __shfl_xor(p_a2, off);
        p_ab += __shfl_xor(p_ab, off);
    }
    const int wid = tid >> 6;
    if ((tid & 63) == 0) { red[wid] = p_a2; red[4 + wid] = p_ab; }
    __syncthreads();  // also makes alpha[] visible to everyone
    if (tid == 0) {
        kqq[s] = red[0] + red[1] + red[2] + red[3];
        sl[s]  = red[4] + red[5] + red[6] + red[7];
        invl[s] = 1.0 / (double)(s + 1);
    }

    // ---- adjacency dots: wave 0 -> kq_adj[s+1], wave 1 -> vv_adj[s] ----
    if (tid < 64) {
        if (s + 1 < SEQ) {
            float p2 = ks[tid] * q[(size_t)(s + 1) * D + tid]
                     + ks[tid + 64] * q[(size_t)(s + 1) * D + 64 + tid];
#pragma unroll
            for (int off = 1; off < 64; off <<= 1) p2 += __shfl_xor(p2, off);
            if (tid == 0) kq_adj[s + 1] = p2;
        }
        if (s == 0 && tid == 0) { kq_adj[0] = 0.f; kU_adj[0] = 0.f; vv_adj[0] = 0.f; }
    } else if (tid < 128 && s > 0) {
        const int t2 = tid - 64;
        float p2 = vs[t2] * v[(size_t)(s - 1) * D + t2]
                 + vs[t2 + 64] * v[(size_t)(s - 1) * D + 64 + t2];
#pragma unroll
        for (int off = 1; off < 64; off <<= 1) p2 += __shfl_xor(p2, off);
        if (t2 == 0) vv_adj[s] = p2;
    }

    // pass 2: U[s][c] = sum_i q[i][c] * alpha[i]
    const int c = tid & (D - 1);
    const int h = tid >> 7;  // 0 or 1
    float a0 = 0.f, a1 = 0.f, a2 = 0.f, a3 = 0.f;
    int i = h;
    for (; i + 6 <= s; i += 8) {
        a0 = fmaf(q[(size_t)(i    ) * D + c], alpha[i    ], a0);
        a1 = fmaf(q[(size_t)(i + 2) * D + c], alpha[i + 2], a1);
        a2 = fmaf(q[(size_t)(i + 4) * D + c], alpha[i + 4], a2);
        a3 = fmaf(q[(size_t)(i + 6) * D + c], alpha[i + 6], a3);
    }
    for (; i <= s; i += 2) a0 = fmaf(q[(size_t)i * D + c], alpha[i], a0);
    upart[tid] = (a0 + a1) + (a2 + a3);
    __syncthreads();

    // U store + kU_adj[s] = k_{s-1}.U_s
    float kup = 0.f;
    if (tid < D) {
        const float uv = upart[tid] + upart[tid + D];
        U[(size_t)s * D + tid] = uv;
        if (s > 0) kup = uv * k[(size_t)(s - 1) * D + tid];
    }
#pragma unroll
    for (int off = 1; off < 64; off <<= 1) kup += __shfl_xor(kup, off);
    if (tid == 0)  red[0] = kup;
    if (tid == 64) red[1] = kup;
    __syncthreads();
    if (s > 0 && tid == 0) kU_adj[s] = red[0] + red[1];
}

// ---------------------------------------------------------------------------
// DPP helpers: all ops here are EXACT cross-lane sums (quad_perm pair/quad,
// row_half_mirror, row_mirror) -- no row_bcast ops, so no hidden scale factor
// and the old *0.125 compensation is dropped (r's are exact sums now).
// ---------------------------------------------------------------------------
#define DPP_ADD(x, ctrl) \
    ((x) + __int_as_float(__builtin_amdgcn_update_dpp(0, __float_as_int(x), (ctrl), 0xf, 0xf, true)))
#define REDUCE16(x) do { x = DPP_ADD(x, 0xB1); x = DPP_ADD(x, 0x4E); \
                         x = DPP_ADD(x, 0x141); x = DPP_ADD(x, 0x140); } while (0)

// packed-fp32 rank-1 update for the 4-row x 8-col per-lane J tile.
// uses jA0..jD3, k0_..k3_, vc4 from enclosing scope
#define UPDATE_J(MODE, WF, WI)                                                \
    if ((MODE) == 2) {                                                        \
        const v2f wA = {vc4.x, vc4.x}, wB = {vc4.y, vc4.y};                   \
        const v2f wC = {vc4.z, vc4.z}, wD = {vc4.w, vc4.w};                   \
        jA0 = wA * k0_; jA1 = wA * k1_; jA2 = wA * k2_; jA3 = wA * k3_;       \
        jB0 = wB * k0_; jB1 = wB * k1_; jB2 = wB * k2_; jB3 = wB * k3_;       \
        jC0 = wC * k0_; jC1 = wC * k1_; jC2 = wC * k2_; jC3 = wC * k3_;       \
        jD0 = wD * k0_; jD1 = wD * k1_; jD2 = wD * k2_; jD3 = wD * k3_;       \
    } else if ((MODE) == 1) {                                                 \
        const v2f wf2 = {(WF), (WF)};                                         \
        const float sA = (WI) * vc4.x, sB = (WI) * vc4.y;                     \
        const float sC = (WI) * vc4.z, sD = (WI) * vc4.w;                     \
        const v2f wA = {sA, sA}, wB = {sB, sB}, wC = {sC, sC}, wD = {sD, sD}; \
        jA0 = __builtin_elementwise_fma(jA0, wf2, wA * k0_);                  \
        jA1 = __builtin_elementwise_fma(jA1, wf2, wA * k1_);                  \
        jA2 = __builtin_elementwise_fma(jA2, wf2, wA * k2_);                  \
        jA3 = __builtin_elementwise_fma(jA3, wf2, wA * k3_);                  \
        jB0 = __builtin_elementwise_fma(jB0, wf2, wB * k0_);                  \
        jB1 = __builtin_elementwise_fma(jB1, wf2, wB * k1_);                  \
        jB2 = __builtin_elementwise_fma(jB2, wf2, wB * k2_);                  \
        jB3 = __builtin_elementwise_fma(jB3, wf2, wB * k3_);                  \
        jC0 = __builtin_elementwise_fma(jC0, wf2, wC * k0_);                  \
        jC1 = __builtin_elementwise_fma(jC1, wf2, wC * k1_);                  \
        jC2 = __builtin_elementwise_fma(jC2, wf2, wC * k2_);                  \
        jC3 = __builtin_elementwise_fma(jC3, wf2, wC * k3_);                  \
        jD0 = __builtin_elementwise_fma(jD0, wf2, wD * k0_);                  \
        jD1 = __builtin_elementwise_fma(jD1, wf2, wD * k1_);                  \
        jD2 = __builtin_elementwise_fma(jD2, wf2, wD * k2_);                  \
        jD3 = __builtin_elementwise_fma(jD3, wf2, wD * k3_);                  \
    }

// ---------------------------------------------------------------------------
// Kernel 2: sequential scan, 1024 threads (16 waves).
// ROUND-16: the R15 kernel was LDS-return-BW bound (48 operand floats/lane/
// step x 1024 lanes ~ 196KB/step ~ 1536cy at 128B/clk) with wave0's serial
// fp64 chain stacked on top of its own dots. Restructure:
//   wave 0      : decision chain ONLY (no J, no dots) -> chain overlaps dots
//   wave 1      : v ring stager
//   waves 2..7  : q/U/k ring stagers (as before)
//   waves 8..15 : own J, 32 el/lane as 4 rows x 8 cols -> operand traffic
//                 drops to 128B/lane/step x 512 lanes ~ 64KB/step (3x cut).
// Row sums via exact 16-lane DPP reduce; 32-entry wred reduced exactly on
// wave0 (two reads + add + REDUCE16) -> the old 0.125 factor is gone.
// ---------------------------------------------------------------------------
__global__ __launch_bounds__(1024, 4) void scan_kernel(
    const float* __restrict__ q, const float* __restrict__ k, const float* __restrict__ v,
    const float* __restrict__ U, const float* __restrict__ sl_arr,
    const float* __restrict__ kqq_arr, const float* __restrict__ vv_arr,
    const float* __restrict__ kq_adj, const float* __restrict__ vv_adj,
    const float* __restrict__ kU_adj, const double* __restrict__ invl_arr,
    float* __restrict__ out)  // [0,2048) costs | [2048,4096) updated | [4096,...) J
{
    const int tid  = threadIdx.x;
    const int lane = tid & 63;
    const int w    = __builtin_amdgcn_readfirstlane(tid >> 6);  // 0..15

    __shared__ float ring[3][4][160];                 // [phase][q,u,k,v][swizzled]
    __shared__ __align__(16) float wred[3][32][4];    // [phase][entry][z1..z4]
    __shared__ __align__(16) float decLDS[3][4];      // [phase][wf,wi,mode,-]

    // ---- roles ----
    const bool isj     = (tid >= 512);                 // waves 8..15: J owners
    const int  jw      = w - 8;                        // 0..7 (valid when isj)
    const int  i16     = lane & 15;                    // col-chunk 0..15
    const int  r4      = lane >> 4;                    // DPP-row 0..3
    const int  o       = 20 * (i16 >> 1) + 8 * (i16 & 1);  // 8-float window (swizzled)
    const int  rb      = (jw << 4) + (r4 << 2);        // first of my 4 rows
    const int  vo      = 20 * jw + (r4 << 2);          // my v window (swizzled)

    const bool stager  = (tid >= 128) && (tid < 512);  // waves 2..7: q/U/k
    const int  which   = (tid >> 7) - 1;               // 0:q 1:u 2:k
    const int  sidx    = tid & 127;
    const int  widx    = ((sidx >> 4) * 20) + (sidx & 15);

    const bool vstager = (tid >= 64) && (tid < 128);   // wave 1: v
    const int  s2      = tid & 63;
    const int  vc0     = 2 * s2;
    const int  vwidx   = 20 * (vc0 >> 4) + (vc0 & 15);

    // J tile registers: row A..D (rb+0..3) x 4 col-pairs
    v2f jA0 = {0.f, 0.f}, jA1 = jA0, jA2 = jA0, jA3 = jA0;
    v2f jB0 = jA0, jB1 = jA0, jB2 = jA0, jB3 = jA0;
    v2f jC0 = jA0, jC1 = jA0, jC2 = jA0, jC3 = jA0;
    v2f jD0 = jA0, jD1 = jA0, jD2 = jA0, jD3 = jA0;
    v4f vc4 = {0.f, 0.f, 0.f, 0.f}, vn4 = vc4;         // v_I, v_{I+1} for my 4 rows

    // ---- prologue: stage phases 0,1; gstage/gv hold phase-2 data ----
    // invariant: phase j holds q_{j+1}, U_{j+1}, k_j, v_{j+1}
    float gstage = 0.f;
    v2f   gv = {0.f, 0.f};
    if (stager) {
        if (which == 0) {
            ring[0][0][widx] = q[(size_t)1 * D + sidx];
            ring[1][0][widx] = q[(size_t)2 * D + sidx];
            gstage = q[(size_t)3 * D + sidx];
        } else if (which == 1) {
            ring[0][1][widx] = U[(size_t)1 * D + sidx];
            ring[1][1][widx] = U[(size_t)2 * D + sidx];
            gstage = U[(size_t)3 * D + sidx];
        } else {
            ring[0][2][widx] = k[sidx];
            ring[1][2][widx] = k[(size_t)1 * D + sidx];
            gstage = k[(size_t)2 * D + sidx];
        }
    } else if (vstager) {
        *(v2f*)&ring[0][3][vwidx] = *(const v2f*)&v[(size_t)1 * D + vc0];
        *(v2f*)&ring[1][3][vwidx] = *(const v2f*)&v[(size_t)2 * D + vc0];
        gv = *(const v2f*)&v[(size_t)3 * D + vc0];
    } else if (isj) {
        vc4 = *(const v4f*)&v[rb];                     // v_0 for my rows
    }

    // dec_0 is always mode 2 (first step: J_0 = v_0 k_0^T); read at body 0
    float dwf = 0.f, dwi = 1.f;
    int dmode = 2;
    if (tid == 0) { decLDS[0][0] = 0.f; decLDS[0][1] = 1.f; decLDS[0][2] = 2.f; decLDS[0][3] = 0.f; }

    double SJ = 0.0, AJJ = 0.0, trSvv = 0.0;  // live on wave 0 only
    if (w == 0) {
        const double sl0 = (double)sl_arr[0];
        const double kq0 = (double)kqq_arr[0];
        const double vv0 = (double)vv_arr[0];
        trSvv = vv0;
        SJ  = sl0;
        AJJ = vv0 * kq0;
        if (lane == 0) {
            out[0] = (float)((0.5 * trSvv - SJ + 0.5 * AJJ) * invl_arr[0]);
            out[SEQ] = 1.f;
        }
    }
    __syncthreads();

#define STEP_BODY(I, P, PN, PW)                                               \
{                                                                             \
    float c_sl = 0.f, c_kq = 0.f, c_vv = 0.f, c_kqa = 0.f, c_vva = 0.f,       \
          c_vvp = 0.f, c_kua = 0.f;                                           \
    double c_inv = 0.0;                                                       \
    if (w == 0) {                                                             \
        c_sl  = sl_arr[(I) + 1];  c_kq  = kqq_arr[(I) + 1];                   \
        c_vv  = vv_arr[(I) + 1];  c_kqa = kq_adj[(I) + 1];                    \
        c_vva = vv_adj[(I) + 1];  c_vvp = vv_arr[(I)];                        \
        c_kua = kU_adj[(I) + 1];  c_inv = invl_arr[(I) + 1];                  \
    }                                                                         \
    if (isj) {                                                                \
        const v4f Qa = ((const v4f*)&ring[P][0][o])[0];                       \
        const v4f Qb = ((const v4f*)&ring[P][0][o])[1];                       \
        const v4f Ua = ((const v4f*)&ring[P][1][o])[0];                       \
        const v4f Ub = ((const v4f*)&ring[P][1][o])[1];                       \
        vn4 = *((const v4f*)&ring[P][3][vo]);                                 \
        const v2f q0 = LO2(Qa), q1 = HI2(Qa), q2 = LO2(Qb), q3 = HI2(Qb);     \
        v2f aA = jA0 * q0, aB = jB0 * q0, aC = jC0 * q0, aD = jD0 * q0;       \
        aA = __builtin_elementwise_fma(jA1, q1, aA);                          \
        aB = __builtin_elementwise_fma(jB1, q1, aB);                          \
        aC = __builtin_elementwise_fma(jC1, q1, aC);                          \
        aD = __builtin_elementwise_fma(jD1, q1, aD);                          \
        aA = __builtin_elementwise_fma(jA2, q2, aA);                          \
        aB = __builtin_elementwise_fma(jB2, q2, aB);                          \
        aC = __builtin_elementwise_fma(jC2, q2, aC);                          \
        aD = __builtin_elementwise_fma(jD2, q2, aD);                          \
        aA = __builtin_elementwise_fma(jA3, q3, aA);                          \
        aB = __builtin_elementwise_fma(jB3, q3, aB);                          \
        aC = __builtin_elementwise_fma(jC3, q3, aC);                          \
        aD = __builtin_elementwise_fma(jD3, q3, aD);                          \
        float YqA = aA.x + aA.y, YqB = aB.x + aB.y;                           \
        float YqC = aC.x + aC.y, YqD = aD.x + aD.y;                           \
        const v2f u0 = LO2(Ua), u1 = HI2(Ua), u2 = LO2(Ub), u3 = HI2(Ub);     \
        v2f bA = jA0 * u0, bB = jB0 * u0, bC = jC0 * u0, bD = jD0 * u0;       \
        bA = __builtin_elementwise_fma(jA1, u1, bA);                          \
        bB = __builtin_elementwise_fma(jB1, u1, bB);                          \
        bC = __builtin_elementwise_fma(jC1, u1, bC);                          \
        bD = __builtin_elementwise_fma(jD1, u1, bD);                          \
        bA = __builtin_elementwise_fma(jA2, u2, bA);                          \
        bB = __builtin_elementwise_fma(jB2, u2, bB);                          \
        bC = __builtin_elementwise_fma(jC2, u2, bC);                          \
        bD = __builtin_elementwise_fma(jD2, u2, bD);                          \
        bA = __builtin_elementwise_fma(jA3, u3, bA);                          \
        bB = __builtin_elementwise_fma(jB3, u3, bB);                          \
        bC = __builtin_elementwise_fma(jC3, u3, bC);                          \
        bD = __builtin_elementwise_fma(jD3, u3, bD);                          \
        float YwA = bA.x + bA.y, YwB = bB.x + bB.y;                           \
        float YwC = bC.x + bC.y, YwD = bD.x + bD.y;                           \
        REDUCE16(YqA); REDUCE16(YqB); REDUCE16(YqC); REDUCE16(YqD);           \
        REDUCE16(YwA); REDUCE16(YwB); REDUCE16(YwC); REDUCE16(YwD);           \
        const float z1 = (vn4.x * YqA + vn4.y * YqB) + (vn4.z * YqC + vn4.w * YqD); \
        const float z2 = (YqA * YqA + YqB * YqB) + (YqC * YqC + YqD * YqD);   \
        const float z3 = (vc4.x * YqA + vc4.y * YqB) + (vc4.z * YqC + vc4.w * YqD); \
        const float z4 = (vn4.x * YwA + vn4.y * YwB) + (vn4.z * YwC + vn4.w * YwD); \
        if ((lane & 15) == 15)                                                \
            *(float4*)&wred[P][(jw << 2) | r4][0] = make_float4(z1, z2, z3, z4); \
    }                                                                         \
    __syncthreads();                                                          \
    if (stager) {                                                             \
        ring[PW][which][widx] = gstage;                                       \
        const int tq_ = ((I) + 4 < SEQ) ? (I) + 4 : SEQ - 1;                  \
        const int tk_ = ((I) + 3 < SEQ) ? (I) + 3 : SEQ - 1;                  \
        gstage = (which == 0) ? q[(size_t)tq_ * D + sidx]                     \
               : (which == 1) ? U[(size_t)tq_ * D + sidx]                     \
                              : k[(size_t)tk_ * D + sidx];                    \
    } else if (vstager) {                                                     \
        *(v2f*)&ring[PW][3][vwidx] = gv;                                      \
        const int tv_ = ((I) + 4 < SEQ) ? (I) + 4 : SEQ - 1;                  \
        gv = *(const v2f*)&v[(size_t)tv_ * D + vc0];                          \
    } else if (isj) {                                                         \
        const float4 df = *(const float4*)&decLDS[P][0];                      \
        const v4f Ka = ((const v4f*)&ring[P][2][o])[0];                       \
        const v4f Kb = ((const v4f*)&ring[P][2][o])[1];                       \
        const v2f k0_ = LO2(Ka), k1_ = HI2(Ka), k2_ = LO2(Kb), k3_ = HI2(Kb); \
        const float uwf = df.x, uwi = df.y;                                   \
        const int   umode = (int)df.z;                                        \
        UPDATE_J(umode, uwf, uwi)                                             \
        vc4 = vn4;                                                            \
    } else if (w == 0) {                                                      \
        const float4 wa = *(const float4*)&wred[P][lane & 15][0];             \
        const float4 wb = *(const float4*)&wred[P][16 + (lane & 15)][0];      \
        float4 ww = make_float4(wa.x + wb.x, wa.y + wb.y,                     \
                                wa.z + wb.z, wa.w + wb.w);                    \
        const float odwf = dwf, odwi = dwi;                                   \
        const int   odmode = dmode;                                           \
        REDUCE16(ww.x);                                                       \
        REDUCE16(ww.y);                                                       \
        REDUCE16(ww.z);                                                       \
        REDUCE16(ww.w);                                                       \
        double a_, b_;                                                        \
        if (odmode == 2)      { a_ = 0.0; b_ = 1.0; }                         \
        else if (odmode == 1) { a_ = (double)odwf; b_ = (double)odwi; }       \
        else                  { a_ = 1.0; b_ = 0.0; }                         \
        const double kqa = (double)c_kqa, vva = (double)c_vva;                \
        const double vvp = (double)c_vvp, kua = (double)c_kua;                \
        const double r1 = (double)ww.x, r2 = (double)ww.y;                    \
        const double r3 = (double)ww.z, r4_ = (double)ww.w;                   \
        const double Jqv  = a_ * r1 + b_ * (kqa * vva);                       \
        const double Jq2  = a_ * a_ * r2 + 2.0 * a_ * b_ * kqa * r3          \
                          + b_ * b_ * kqa * kqa * vvp;                        \
        const double AJl_ = a_ * r4_ + b_ * kua * vva;                        \
        trSvv += (double)c_vv;                                                \
        SJ    += Jqv;                                                         \
        AJJ   += Jq2;                                                         \
        const double s_l  = (double)c_sl;                                     \
        const double A_ll = (double)c_vv * (double)c_kq;                      \
        const double AJJ_s  = (AJJ == 0.0)  ? 1.0 : AJJ;                      \
        const double A_ll_s = (A_ll == 0.0) ? 1.0 : A_ll;                     \
        const double denom   = AJJ * A_ll - AJl_ * AJl_;                      \
        const double denom_s = (denom == 0.0) ? 1.0 : denom;                  \
        const double rden = 1.0 / denom_s;                                    \
        const double wf = (A_ll * SJ - AJl_ * s_l) * rden;                    \
        const double wi = (AJJ * s_l - AJl_ * SJ) * rden;                     \
        double wf_c, wi_c;                                                    \
        if (wi <= 0.0)      { wf_c = SJ / AJJ_s;  wi_c = 0.0; }               \
        else if (wf <= 0.0) { wf_c = 0.0;         wi_c = s_l / A_ll_s; }      \
        else                { wf_c = wf;          wi_c = wi; }                \
        const bool do_update = (s_l * AJJ_s - AJl_ * SJ) > 0.0;               \
        int mode;                                                             \
        if (do_update) {                                                      \
            mode = 1;                                                         \
            const double nSJ = wf_c * SJ + wi_c * s_l;                        \
            AJJ = wf_c * wf_c * AJJ + 2.0 * wf_c * wi_c * AJl_                \
                + wi_c * wi_c * A_ll;                                         \
            SJ = nSJ;                                                         \
        } else {                                                              \
            mode = 0;                                                         \
        }                                                                     \
        dwf = (float)wf_c; dwi = (float)wi_c; dmode = mode;                   \
        if (lane == 0) {                                                      \
            out[(I) + 1] = (float)((0.5 * trSvv - SJ + 0.5 * AJJ) * c_inv);   \
            out[SEQ + (I) + 1] = mode ? 1.f : 0.f;                            \
            *(float4*)&decLDS[PN][0] = make_float4(dwf, dwi, (float)mode, 0.f);\
        }                                                                     \
    }                                                                         \
}

    // bodies I = 0..SEQ-2 (2047 of them): 682 x3-unrolled + 1 tail (2046%3==0)
    for (int i = 0; i + 2 < SEQ - 1; i += 3) {
        STEP_BODY(i,     0, 1, 2)
        STEP_BODY(i + 1, 1, 2, 0)
        STEP_BODY(i + 2, 2, 0, 1)
    }
    STEP_BODY(SEQ - 2, 0, 1, 2)
#undef STEP_BODY

    // ---- epilogue: apply final update (dec_{SEQ-1}, phase (SEQ-1)%3 = 1) ----
    __syncthreads();  // make wave0's decLDS[1] write visible
    if (isj) {
        const float4 df = *(const float4*)&decLDS[1][0];
        const float fwf = df.x, fwi = df.y;
        const int   fmode = (int)df.z;
        const v4f Ka = ((const v4f*)&ring[1][2][o])[0];
        const v4f Kb = ((const v4f*)&ring[1][2][o])[1];
        const v2f k0_ = LO2(Ka), k1_ = HI2(Ka), k2_ = LO2(Kb), k3_ = HI2(Kb);
        UPDATE_J(fmode, fwf, fwi)
        float* jb = out + 2 * SEQ + (size_t)rb * D + 8 * i16;
        *(v4f*)(jb + 0)         = __builtin_shufflevector(jA0, jA1, 0, 1, 2, 3);
        *(v4f*)(jb + 4)         = __builtin_shufflevector(jA2, jA3, 0, 1, 2, 3);
        *(v4f*)(jb + D + 0)     = __builtin_shufflevector(jB0, jB1, 0, 1, 2, 3);
        *(v4f*)(jb + D + 4)     = __builtin_shufflevector(jB2, jB3, 0, 1, 2, 3);
        *(v4f*)(jb + 2 * D + 0) = __builtin_shufflevector(jC0, jC1, 0, 1, 2, 3);
        *(v4f*)(jb + 2 * D + 4) = __builtin_shufflevector(jC2, jC3, 0, 1, 2, 3);
        *(v4f*)(jb + 3 * D + 0) = __builtin_shufflevector(jD0, jD1, 0, 1, 2, 3);
        *(v4f*)(jb + 3 * D + 4) = __builtin_shufflevector(jD2, jD3, 0, 1, 2, 3);
    }
}

extern "C" void kernel_launch(void* const* d_in, const int* in_sizes, int n_in,
                              void* d_out, int out_size, void* d_ws, size_t ws_size,
                              hipStream_t stream) {
    (void)in_sizes; (void)n_in; (void)out_size; (void)ws_size;
    const float* q = (const float*)d_in[0];
    const float* k = (const float*)d_in[1];
    const float* v = (const float*)d_in[2];
    float* out = (float*)d_out;

    float* U      = (float*)d_ws;            // SEQ*D floats (1 MB)
    float* sl     = U + (size_t)SEQ * D;     // SEQ
    float* kqq    = sl + SEQ;                // SEQ
    float* vv     = kqq + SEQ;               // SEQ
    float* kq_adj = vv + SEQ;                // SEQ
    float* vv_adj = kq_adj + SEQ;            // SEQ
    float* kU_adj = vv_adj + SEQ;            // SEQ
    double* invl  = (double*)(kU_adj + SEQ); // SEQ doubles (8B-aligned)

    precompute_kernel<<<SEQ, 256, 0, stream>>>(q, k, v, U, sl, kqq, vv,
                                               kq_adj, vv_adj, kU_adj, invl);
    scan_kernel<<<1, 1024, 0, stream>>>(q, k, v, U, sl, kqq, vv,
                                        kq_adj, vv_adj, kU_adj, invl, out);
}